// Round 4
// baseline (543.125 us; speedup 1.0000x reference)
//
#include <hip/hip_runtime.h>
#include <hip/hip_bf16.h>
#include <math.h>

#define TSEQ   2048
#define BATCH  4
#define DIM    1024
#define NH     16
#define HD     64
#define MTOT   (BATCH*TSEQ)   // 8192
#define LDQKV  (3*DIM)        // fused qkv row stride

typedef __attribute__((ext_vector_type(8))) short bf16x8;   // 8 bf16 = 4 VGPRs
typedef __attribute__((ext_vector_type(4))) float f32x4;

__device__ __forceinline__ unsigned short f2bf(float f) {
    unsigned int b = __float_as_uint(f);
    b = (b + 0x7fffu + ((b >> 16) & 1u)) >> 16;   // RTN-even
    return (unsigned short)b;
}

// async global->LDS, 16B per lane; LDS dest = wave-uniform base + lane*16
__device__ __forceinline__ void glds16(const void* g, void* l) {
    __builtin_amdgcn_global_load_lds(
        (const __attribute__((address_space(1))) void*)g,
        (__attribute__((address_space(3))) void*)l, 16, 0, 0);
}

// ---------------------------------------------------------------------------
// x fp32 -> bf16, 8 elems/thread
// ---------------------------------------------------------------------------
__global__ __launch_bounds__(256)
void cvt_x(const float* __restrict__ in, unsigned short* __restrict__ out, int n8)
{
    int i = blockIdx.x * 256 + threadIdx.x;
    if (i >= n8) return;
    const float4* p = (const float4*)in + 2 * (size_t)i;
    float4 a = p[0], b = p[1];
    bf16x8 o;
    o[0] = (short)f2bf(a.x); o[1] = (short)f2bf(a.y);
    o[2] = (short)f2bf(a.z); o[3] = (short)f2bf(a.w);
    o[4] = (short)f2bf(b.x); o[5] = (short)f2bf(b.y);
    o[6] = (short)f2bf(b.z); o[7] = (short)f2bf(b.w);
    *((bf16x8*)out + i) = o;
}

// ---------------------------------------------------------------------------
// W fp32 [K][N] -> WT bf16 [N][K] (transposed), 32x32 LDS tiles
// ---------------------------------------------------------------------------
__global__ __launch_bounds__(256)
void cvt_tr(const float* __restrict__ W, unsigned short* __restrict__ WT)
{
    __shared__ float t[32][33];
    const int x = threadIdx.x, y0 = threadIdx.y;   // 32 x 8
    const int bx = blockIdx.x, by = blockIdx.y;
#pragma unroll
    for (int j = 0; j < 4; ++j)
        t[y0 + j*8][x] = W[(size_t)(by*32 + y0 + j*8) * DIM + bx*32 + x];
    __syncthreads();
#pragma unroll
    for (int j = 0; j < 4; ++j)
        WT[(size_t)(bx*32 + y0 + j*8) * DIM + by*32 + x] = f2bf(t[x][y0 + j*8]);
}

// ---------------------------------------------------------------------------
// GEMM (m97 structure): C[M,N] = A[M,K] @ BT[N,K]^T (+bias). bf16 16x16x32.
// 128x128 tile, BK=32, 4 waves. Staging via global_load_lds dwordx4:
// LDS dest LINEAR [row][32]; chunk swizzle c' = c ^ ((row>>1)&3) applied by
// pre-swizzling the GLOBAL source chunk (rule 21); reads use swizzled addr.
// ---------------------------------------------------------------------------
template<bool F32OUT>
__global__ __launch_bounds__(256)
void gemm_glds(const unsigned short* __restrict__ A, const unsigned short* __restrict__ BT,
               const float* __restrict__ bias, void* __restrict__ Cout,
               const int M, const int N, const int K)
{
    __shared__ unsigned short As[128*32];
    __shared__ unsigned short Bs[128*32];
    const int t = threadIdx.x;
    const int w = t >> 6, lane = t & 63, g = lane >> 4, li = lane & 15;
    const int wm = (w >> 1) * 64, wn = (w & 1) * 64;
    const int m0 = blockIdx.x * 128, n0 = blockIdx.y * 128;

    f32x4 acc[4][4] = {};

    // wave w stages rows [w*32, w*32+32), two 16-row glds issues per operand.
    const int r_a  = w*32 + (lane >> 2);        // issue-0 row
    const int r_b  = r_a + 16;                  // issue-1 row
    const int slot = lane & 3;                  // LDS chunk slot (linear)
    const int sc0  = slot ^ ((r_a >> 1) & 3);   // pre-swizzled source chunk
    const int sc1  = slot ^ ((r_b >> 1) & 3);

    const unsigned short* Ap0 = &A [(size_t)(m0 + r_a) * K + sc0*8];
    const unsigned short* Ap1 = &A [(size_t)(m0 + r_b) * K + sc1*8];
    const unsigned short* Bp0 = &BT[(size_t)(n0 + r_a) * K + sc0*8];
    const unsigned short* Bp1 = &BT[(size_t)(n0 + r_b) * K + sc1*8];
    unsigned short* AsW0 = &As[w*1024];         // 32 rows * 32 elems
    unsigned short* AsW1 = &As[w*1024 + 512];
    unsigned short* BsW0 = &Bs[w*1024];
    unsigned short* BsW1 = &Bs[w*1024 + 512];

    char* AsB = (char*)As;
    char* BsB = (char*)Bs;

    for (int kt = 0; kt < K; kt += 32) {
        __syncthreads();                         // prev frag reads done
        glds16(Ap0 + kt, AsW0);
        glds16(Ap1 + kt, AsW1);
        glds16(Bp0 + kt, BsW0);
        glds16(Bp1 + kt, BsW1);
        __syncthreads();                         // compiler drains vmcnt(0) first

        bf16x8 af[4], bfv[4];
#pragma unroll
        for (int mi = 0; mi < 4; ++mi) {
            const int r = wm + mi*16 + li;
            af[mi] = *(const bf16x8*)(AsB + r*64 + ((g ^ ((r >> 1) & 3)) * 16));
        }
#pragma unroll
        for (int ni = 0; ni < 4; ++ni) {
            const int r = wn + ni*16 + li;
            bfv[ni] = *(const bf16x8*)(BsB + r*64 + ((g ^ ((r >> 1) & 3)) * 16));
        }
#pragma unroll
        for (int mi = 0; mi < 4; ++mi)
#pragma unroll
            for (int ni = 0; ni < 4; ++ni)
                acc[mi][ni] = __builtin_amdgcn_mfma_f32_16x16x32_bf16(
                    af[mi], bfv[ni], acc[mi][ni], 0, 0, 0);
    }

    // epilogue: D row = 4*g + reg, col = li (per 16x16 tile)
#pragma unroll
    for (int mi = 0; mi < 4; ++mi)
#pragma unroll
        for (int ni = 0; ni < 4; ++ni) {
            const int gr = m0 + wm + mi*16 + 4*g;
            const int gc = n0 + wn + ni*16 + li;
#pragma unroll
            for (int r = 0; r < 4; ++r) {
                const float v = acc[mi][ni][r];
                if (F32OUT)
                    ((float*)Cout)[(size_t)(gr + r) * N + gc] = v + bias[gc];
                else
                    ((unsigned short*)Cout)[(size_t)(gr + r) * N + gc] = f2bf(v);
            }
        }
}

// ---------------------------------------------------------------------------
// Flash attention, bf16 MFMA, 1-barrier pipelined loop.
// Block: 64 q-rows, 4 waves x 16 rows. Double-buffered K (glds, pre-swizzled
// source) and V (reg-staged, scatter-transposed). exp2-domain softmax with
// defer-max (THR=8). Q frags in registers; P via wave-private LDS.
// K/VT LDS [64][64] bf16, row=128B=8 chunks, swizzle c' = c ^ (row&7).
// ---------------------------------------------------------------------------
#define SCL2E 0.18033688f    // (1/sqrt(64)) * log2(e)

__global__ __launch_bounds__(256)
void attn_bf16(const unsigned short* __restrict__ QKV, unsigned short* __restrict__ O)
{
    __shared__ unsigned short Ks[2][64*64];
    __shared__ unsigned short VT[2][64*64];
    __shared__ unsigned short Ps[64*64];
    const int t = threadIdx.x;
    const int w = t >> 6, lane = t & 63, g = lane >> 4, li = lane & 15;
    const int qt = (int)gridDim.x - 1 - (int)blockIdx.x;   // heavy blocks first
    const int bh = blockIdx.y, b = bh >> 4, h = bh & 15;
    const int q0 = qt * 64;
    const size_t rowbase = (size_t)b * TSEQ;
    const int cq = h*HD, ck = DIM + h*HD, cv = 2*DIM + h*HD;

    // Q fragments (rows w*16+li)
    bf16x8 qa[2];
#pragma unroll
    for (int ks = 0; ks < 2; ++ks)
        qa[ks] = *(const bf16x8*)&QKV[(rowbase + q0 + w*16 + li) * LDQKV + cq + 8*g + 32*ks];

    f32x4 ctx[4] = {};
    float m_i[4], l_i[4];
#pragma unroll
    for (int r = 0; r < 4; ++r) { m_i[r] = -INFINITY; l_i[r] = 0.f; }

    char* PsB = (char*)Ps;

    // K glds mapping: wave w issue j covers rows 16w+8j + (lane>>3), slot lane&7,
    // pre-swizzled source chunk (lane&7)^(lane>>3); LDS dest (2w+j)*512 elems.
    const int krow   = lane >> 3;
    const int kchunk = (lane & 7) ^ krow;
    const int kr0 = 16*w + krow, kr1 = 16*w + 8 + krow;
    // V reg staging: thread covers kv-row t&63, d-chunks 2w and 2w+1
    const int kvr = t & 63;
    const int dc0 = 2*w, dc1 = 2*w + 1;

    // ---- prologue: stage tile 0 into buffer 0
    {
        const size_t nb = rowbase;   // kv = 0
        glds16(&QKV[(nb + kr0) * LDQKV + ck + kchunk*8], &Ks[0][(2*w    )*512]);
        glds16(&QKV[(nb + kr1) * LDQKV + ck + kchunk*8], &Ks[0][(2*w + 1)*512]);
        bf16x8 v0 = *(const bf16x8*)&QKV[(nb + kvr) * LDQKV + cv + dc0*8];
        bf16x8 v1 = *(const bf16x8*)&QKV[(nb + kvr) * LDQKV + cv + dc1*8];
        char* VTB = (char*)VT[0];
#pragma unroll
        for (int j = 0; j < 8; ++j) {
            const int d0 = dc0*8 + j, d1 = dc1*8 + j;
            *(unsigned short*)(VTB + d0*128 + (((kvr >> 3) ^ (d0 & 7)) * 16) + (kvr & 7)*2) = (unsigned short)v0[j];
            *(unsigned short*)(VTB + d1*128 + (((kvr >> 3) ^ (d1 & 7)) * 16) + (kvr & 7)*2) = (unsigned short)v1[j];
        }
    }
    __syncthreads();

    int cur = 0;
    for (int kv = 0; kv <= qt; ++kv) {
        // ---- issue next tile's loads first (fly under compute)
        bf16x8 vn0, vn1;
        if (kv < qt) {
            const size_t nb = rowbase + (size_t)(kv + 1) * 64;
            glds16(&QKV[(nb + kr0) * LDQKV + ck + kchunk*8], &Ks[cur^1][(2*w    )*512]);
            glds16(&QKV[(nb + kr1) * LDQKV + ck + kchunk*8], &Ks[cur^1][(2*w + 1)*512]);
            vn0 = *(const bf16x8*)&QKV[(nb + kvr) * LDQKV + cv + dc0*8];
            vn1 = *(const bf16x8*)&QKV[(nb + kvr) * LDQKV + cv + dc1*8];
        }

        char* KsB = (char*)Ks[cur];
        char* VTB = (char*)VT[cur];

        // ---- S = Q K^T : per wave 16x64 strip
        f32x4 s[4] = {};
#pragma unroll
        for (int nt = 0; nt < 4; ++nt) {
            const int r = nt*16 + li;
#pragma unroll
            for (int ks = 0; ks < 2; ++ks) {
                bf16x8 kb = *(const bf16x8*)(KsB + r*128 + (((g + 4*ks) ^ (r & 7)) * 16));
                s[nt] = __builtin_amdgcn_mfma_f32_16x16x32_bf16(qa[ks], kb, s[nt], 0, 0, 0);
            }
        }
#pragma unroll
        for (int nt = 0; nt < 4; ++nt) s[nt] *= SCL2E;   // exp2 domain
        if (kv == qt) {
#pragma unroll
            for (int nt = 0; nt < 4; ++nt) {
                const int kvl = nt*16 + li;
#pragma unroll
                for (int r = 0; r < 4; ++r)
                    if (kvl > w*16 + 4*g + r) s[nt][r] = -INFINITY;
            }
        }

        // ---- online softmax (exp2 + defer-max)
#pragma unroll
        for (int r = 0; r < 4; ++r) {
            float mx = fmaxf(fmaxf(s[0][r], s[1][r]), fmaxf(s[2][r], s[3][r]));
            mx = fmaxf(mx, __shfl_xor(mx, 1));
            mx = fmaxf(mx, __shfl_xor(mx, 2));
            mx = fmaxf(mx, __shfl_xor(mx, 4));
            mx = fmaxf(mx, __shfl_xor(mx, 8));
            if (mx > m_i[r] + 8.f) {             // rescale only on real growth
                const float sc = exp2f(m_i[r] - mx);
                m_i[r] = mx;
                l_i[r] *= sc;
#pragma unroll
                for (int n2 = 0; n2 < 4; ++n2) ctx[n2][r] *= sc;
            }
            const float p0 = exp2f(s[0][r] - m_i[r]), p1 = exp2f(s[1][r] - m_i[r]);
            const float p2 = exp2f(s[2][r] - m_i[r]), p3 = exp2f(s[3][r] - m_i[r]);
            float rs = p0 + p1 + p2 + p3;
            rs += __shfl_xor(rs, 1);
            rs += __shfl_xor(rs, 2);
            rs += __shfl_xor(rs, 4);
            rs += __shfl_xor(rs, 8);
            l_i[r] += rs;
            const int q = w*16 + 4*g + r;
            const int ch = li >> 3, cl = (li & 7)*2, qs = q & 7;
            *(unsigned short*)(PsB + q*128 + (((0 + ch) ^ qs)*16) + cl) = f2bf(p0);
            *(unsigned short*)(PsB + q*128 + (((2 + ch) ^ qs)*16) + cl) = f2bf(p1);
            *(unsigned short*)(PsB + q*128 + (((4 + ch) ^ qs)*16) + cl) = f2bf(p2);
            *(unsigned short*)(PsB + q*128 + (((6 + ch) ^ qs)*16) + cl) = f2bf(p3);
        }

        // ---- PV (Ps strip wave-private: no barrier)
        bf16x8 pa[2];
#pragma unroll
        for (int ks = 0; ks < 2; ++ks) {
            const int r = w*16 + li;
            pa[ks] = *(const bf16x8*)(PsB + r*128 + (((g + 4*ks) ^ (r & 7)) * 16));
        }
#pragma unroll
        for (int n2 = 0; n2 < 4; ++n2) {
            const int r = n2*16 + li;
#pragma unroll
            for (int ks = 0; ks < 2; ++ks) {
                bf16x8 vb = *(const bf16x8*)(VTB + r*128 + (((g + 4*ks) ^ (r & 7)) * 16));
                ctx[n2] = __builtin_amdgcn_mfma_f32_16x16x32_bf16(pa[ks], vb, ctx[n2], 0, 0, 0);
            }
        }

        // ---- write next V tile, single barrier, swap
        if (kv < qt) {
            char* VTN = (char*)VT[cur^1];
#pragma unroll
            for (int j = 0; j < 8; ++j) {
                const int d0 = dc0*8 + j, d1 = dc1*8 + j;
                *(unsigned short*)(VTN + d0*128 + (((kvr >> 3) ^ (d0 & 7)) * 16) + (kvr & 7)*2) = (unsigned short)vn0[j];
                *(unsigned short*)(VTN + d1*128 + (((kvr >> 3) ^ (d1 & 7)) * 16) + (kvr & 7)*2) = (unsigned short)vn1[j];
            }
            __syncthreads();   // drains glds (vmcnt) + makes VT writes visible
            cur ^= 1;
        }
    }

    // ---- normalize + write bf16 ctx
#pragma unroll
    for (int r = 0; r < 4; ++r) {
        const float inv = 1.f / l_i[r];
        const size_t row = rowbase + q0 + w*16 + 4*g + r;
#pragma unroll
        for (int n2 = 0; n2 < 4; ++n2)
            O[row * DIM + h*HD + n2*16 + li] = f2bf(ctx[n2][r] * inv);
    }
}

// ---------------------------------------------------------------------------
extern "C" void kernel_launch(void* const* d_in, const int* in_sizes, int n_in,
                              void* d_out, int out_size, void* d_ws, size_t ws_size,
                              hipStream_t stream)
{
    const float* x  = (const float*)d_in[0];
    const float* Wq = (const float*)d_in[1];
    const float* Wk = (const float*)d_in[2];
    const float* Wv = (const float*)d_in[3];
    const float* Wo = (const float*)d_in[4];
    const float* bo = (const float*)d_in[5];
    float* out = (float*)d_out;

    char* ws = (char*)d_ws;
    unsigned short* xb    = (unsigned short*)(ws);                 // 16 MB
    unsigned short* qkv   = (unsigned short*)(ws + (16u << 20));   // 48 MB [8192][3072]
    unsigned short* ctb   = (unsigned short*)(ws + (64u << 20));   // 16 MB
    unsigned short* WTall = (unsigned short*)(ws + (80u << 20));   // 6 MB  [3072][1024]
    unsigned short* WoT   = (unsigned short*)(ws + (86u << 20));   // 2 MB

    cvt_x<<<MTOT*DIM/8/256, 256, 0, stream>>>(x, xb, MTOT*DIM/8);
    dim3 tb(32, 8), tg(32, 32);
    cvt_tr<<<tg, tb, 0, stream>>>(Wq, WTall);                      // rows 0..1023
    cvt_tr<<<tg, tb, 0, stream>>>(Wk, WTall + (size_t)DIM*DIM);    // rows 1024..2047
    cvt_tr<<<tg, tb, 0, stream>>>(Wv, WTall + (size_t)2*DIM*DIM);  // rows 2048..3071
    cvt_tr<<<tg, tb, 0, stream>>>(Wo, WoT);

    // fused Q|K|V projection: [8192,1024] @ [1024,3072] -> [8192,3072]
    gemm_glds<false><<<dim3(MTOT/128, LDQKV/128), 256, 0, stream>>>(
        xb, WTall, nullptr, qkv, MTOT, LDQKV, DIM);

    attn_bf16<<<dim3(TSEQ/64, BATCH*NH), 256, 0, stream>>>(qkv, ctb);

    gemm_glds<true><<<dim3(MTOT/128, DIM/128), 256, 0, stream>>>(
        ctb, WoT, bo, out, MTOT, DIM, DIM);
}

// Round 5
// 363.720 us; speedup vs baseline: 1.4933x; 1.4933x over previous
//
#include <hip/hip_runtime.h>
#include <hip/hip_bf16.h>
#include <math.h>

#define TSEQ   2048
#define BATCH  4
#define DIM    1024
#define NH     16
#define HD     64
#define MTOT   (BATCH*TSEQ)   // 8192
#define LDQKV  (3*DIM)        // fused qkv row stride

typedef __attribute__((ext_vector_type(8))) short bf16x8;   // 8 bf16 = 4 VGPRs
typedef __attribute__((ext_vector_type(4))) float f32x4;

__device__ __forceinline__ unsigned short f2bf(float f) {
    unsigned int b = __float_as_uint(f);
    b = (b + 0x7fffu + ((b >> 16) & 1u)) >> 16;   // RTN-even
    return (unsigned short)b;
}

// packed f32x2 -> bf16x2 (RTNE), dst.lo = lo  [T12 recipe, m214v22-verified]
__device__ __forceinline__ unsigned cvt_pk_bf16(float lo, float hi) {
    unsigned r;
    asm("v_cvt_pk_bf16_f32 %0, %1, %2" : "=v"(r) : "v"(lo), "v"(hi));
    return r;
}

// async global->LDS, 16B per lane; LDS dest = wave-uniform base + lane*16
__device__ __forceinline__ void glds16(const void* g, void* l) {
    __builtin_amdgcn_global_load_lds(
        (const __attribute__((address_space(1))) void*)g,
        (__attribute__((address_space(3))) void*)l, 16, 0, 0);
}

// ---------------------------------------------------------------------------
// x fp32 -> bf16, 8 elems/thread
// ---------------------------------------------------------------------------
__global__ __launch_bounds__(256)
void cvt_x(const float* __restrict__ in, unsigned short* __restrict__ out, int n8)
{
    int i = blockIdx.x * 256 + threadIdx.x;
    if (i >= n8) return;
    const float4* p = (const float4*)in + 2 * (size_t)i;
    float4 a = p[0], b = p[1];
    bf16x8 o;
    o[0] = (short)f2bf(a.x); o[1] = (short)f2bf(a.y);
    o[2] = (short)f2bf(a.z); o[3] = (short)f2bf(a.w);
    o[4] = (short)f2bf(b.x); o[5] = (short)f2bf(b.y);
    o[6] = (short)f2bf(b.z); o[7] = (short)f2bf(b.w);
    *((bf16x8*)out + i) = o;
}

// ---------------------------------------------------------------------------
// W fp32 [K][N] -> WT bf16 [N][K] (transposed), 32x32 LDS tiles
// ---------------------------------------------------------------------------
__global__ __launch_bounds__(256)
void cvt_tr(const float* __restrict__ W, unsigned short* __restrict__ WT)
{
    __shared__ float t[32][33];
    const int x = threadIdx.x, y0 = threadIdx.y;   // 32 x 8
    const int bx = blockIdx.x, by = blockIdx.y;
#pragma unroll
    for (int j = 0; j < 4; ++j)
        t[y0 + j*8][x] = W[(size_t)(by*32 + y0 + j*8) * DIM + bx*32 + x];
    __syncthreads();
#pragma unroll
    for (int j = 0; j < 4; ++j)
        WT[(size_t)(bx*32 + y0 + j*8) * DIM + by*32 + x] = f2bf(t[x][y0 + j*8]);
}

// ---------------------------------------------------------------------------
// GEMM (m97 structure): C[M,N] = A[M,K] @ BT[N,K]^T (+bias). bf16 16x16x32.
// (unchanged from R4)
// ---------------------------------------------------------------------------
template<bool F32OUT>
__global__ __launch_bounds__(256)
void gemm_glds(const unsigned short* __restrict__ A, const unsigned short* __restrict__ BT,
               const float* __restrict__ bias, void* __restrict__ Cout,
               const int M, const int N, const int K)
{
    __shared__ unsigned short As[128*32];
    __shared__ unsigned short Bs[128*32];
    const int t = threadIdx.x;
    const int w = t >> 6, lane = t & 63, g = lane >> 4, li = lane & 15;
    const int wm = (w >> 1) * 64, wn = (w & 1) * 64;
    const int m0 = blockIdx.x * 128, n0 = blockIdx.y * 128;

    f32x4 acc[4][4] = {};

    const int r_a  = w*32 + (lane >> 2);
    const int r_b  = r_a + 16;
    const int slot = lane & 3;
    const int sc0  = slot ^ ((r_a >> 1) & 3);
    const int sc1  = slot ^ ((r_b >> 1) & 3);

    const unsigned short* Ap0 = &A [(size_t)(m0 + r_a) * K + sc0*8];
    const unsigned short* Ap1 = &A [(size_t)(m0 + r_b) * K + sc1*8];
    const unsigned short* Bp0 = &BT[(size_t)(n0 + r_a) * K + sc0*8];
    const unsigned short* Bp1 = &BT[(size_t)(n0 + r_b) * K + sc1*8];
    unsigned short* AsW0 = &As[w*1024];
    unsigned short* AsW1 = &As[w*1024 + 512];
    unsigned short* BsW0 = &Bs[w*1024];
    unsigned short* BsW1 = &Bs[w*1024 + 512];

    char* AsB = (char*)As;
    char* BsB = (char*)Bs;

    for (int kt = 0; kt < K; kt += 32) {
        __syncthreads();
        glds16(Ap0 + kt, AsW0);
        glds16(Ap1 + kt, AsW1);
        glds16(Bp0 + kt, BsW0);
        glds16(Bp1 + kt, BsW1);
        __syncthreads();

        bf16x8 af[4], bfv[4];
#pragma unroll
        for (int mi = 0; mi < 4; ++mi) {
            const int r = wm + mi*16 + li;
            af[mi] = *(const bf16x8*)(AsB + r*64 + ((g ^ ((r >> 1) & 3)) * 16));
        }
#pragma unroll
        for (int ni = 0; ni < 4; ++ni) {
            const int r = wn + ni*16 + li;
            bfv[ni] = *(const bf16x8*)(BsB + r*64 + ((g ^ ((r >> 1) & 3)) * 16));
        }
#pragma unroll
        for (int mi = 0; mi < 4; ++mi)
#pragma unroll
            for (int ni = 0; ni < 4; ++ni)
                acc[mi][ni] = __builtin_amdgcn_mfma_f32_16x16x32_bf16(
                    af[mi], bfv[ni], acc[mi][ni], 0, 0, 0);
    }

#pragma unroll
    for (int mi = 0; mi < 4; ++mi)
#pragma unroll
        for (int ni = 0; ni < 4; ++ni) {
            const int gr = m0 + wm + mi*16 + 4*g;
            const int gc = n0 + wn + ni*16 + li;
#pragma unroll
            for (int r = 0; r < 4; ++r) {
                const float v = acc[mi][ni][r];
                if (F32OUT)
                    ((float*)Cout)[(size_t)(gr + r) * N + gc] = v + bias[gc];
                else
                    ((unsigned short*)Cout)[(size_t)(gr + r) * N + gc] = f2bf(v);
            }
        }
}

// ---------------------------------------------------------------------------
// Flash attention v3: swapped QK^T + permuted K rows -> in-register softmax,
// zero P LDS traffic. Block: 64 q-rows, 4 waves x 16 rows (wave's q = w*16+li).
// S^T = mfma(A=K, B=Q): lane (li,g) holds S[q=li][kv = 32(nt>>1)+4(nt&1)+8g+reg]
// == exactly the PV B-frag k-slots {8g..8g+7}+32*ks2  -> pack with cvt_pk, done.
// K/VT LDS [64 rows][64] bf16, chunk swizzle c' = c ^ swz(r), swz(r)=(r&3)|((r&8)>>1).
// K staged via glds with pre-swizzled global source; V reg-staged + scatter.
// exp2-domain softmax, scale folded into exp fma; defer-max THR=8.
// ---------------------------------------------------------------------------
#define SCL2E 0.18033688f    // (1/sqrt(64)) * log2(e)

__global__ __launch_bounds__(256)
void attn_bf16(const unsigned short* __restrict__ QKV, unsigned short* __restrict__ O)
{
    __shared__ unsigned short Ks[64*64];
    __shared__ unsigned short VT[64*64];
    const int t = threadIdx.x;
    const int w = t >> 6, lane = t & 63, g = lane >> 4, li = lane & 15;
    const int qt = (int)gridDim.x - 1 - (int)blockIdx.x;   // heavy blocks first
    const int bh = blockIdx.y, b = bh >> 4, h = bh & 15;
    const int q0 = qt * 64;
    const size_t rowbase = (size_t)b * TSEQ;
    const int cq = h*HD, ck = DIM + h*HD, cv = 2*DIM + h*HD;

    // Q fragments (B-operand): rows w*16+li, k = 8g + 32ks
    bf16x8 qa[2];
#pragma unroll
    for (int ks = 0; ks < 2; ++ks)
        qa[ks] = *(const bf16x8*)&QKV[(rowbase + q0 + w*16 + li) * LDQKV + cq + 8*g + 32*ks];

    f32x4 ctx[4] = {};               // ctx^T: d = n2*16 + 4g + reg, q = li
    float m_i = -INFINITY, l_i = 0.f;

    char* KsB = (char*)Ks;
    char* VTB = (char*)VT;

    // K glds: wave w issue j covers rows 16w+8j+krow; swz(row) = (krow&3)|(j<<2)
    const int krow = lane >> 3;
    const int kch0 = (lane & 7) ^ (krow & 3);        // j=0
    const int kch1 = kch0 ^ 4;                       // j=1 (bit2 = j)
    const int kr0 = 16*w + krow, kr1 = kr0 + 8;
    // V reg staging: thread covers kv-row `lane`, d-chunks 2w, 2w+1
    const int dc0 = 2*w, dc1 = 2*w + 1;

    for (int kv = 0; kv <= qt; ++kv) {
        const size_t nb = rowbase + (size_t)kv * 64;
        // V global loads issued before the barrier (latency hides under it)
        bf16x8 v0 = *(const bf16x8*)&QKV[(nb + lane) * LDQKV + cv + dc0*8];
        bf16x8 v1 = *(const bf16x8*)&QKV[(nb + lane) * LDQKV + cv + dc1*8];
        __syncthreads();             // all waves done reading prev tile LDS
        glds16(&QKV[(nb + kr0) * LDQKV + ck + kch0*8], &Ks[(2*w    )*512]);
        glds16(&QKV[(nb + kr1) * LDQKV + ck + kch1*8], &Ks[(2*w + 1)*512]);
        // scatter V -> VT[d][kv], swizzled
#pragma unroll
        for (int j = 0; j < 8; ++j) {
            const int d0 = dc0*8 + j, d1 = dc1*8 + j;
            *(unsigned short*)(VTB + d0*128 + (((lane >> 3) ^ ((d0 & 3) | ((d0 & 8) >> 1))) * 16) + (lane & 7)*2) = (unsigned short)v0[j];
            *(unsigned short*)(VTB + d1*128 + (((lane >> 3) ^ ((d1 & 3) | ((d1 & 8) >> 1))) * 16) + (lane & 7)*2) = (unsigned short)v1[j];
        }
        __syncthreads();             // glds drained (vmcnt) + VT visible

        // ---- S^T = K Q^T with permuted A rows
        f32x4 s[4] = {};
#pragma unroll
        for (int nt = 0; nt < 4; ++nt) {
            const int r  = 32*(nt >> 1) + 4*(nt & 1) + 8*(li >> 2) + (li & 3);
            const int sz = (r & 3) | ((r & 8) >> 1);
#pragma unroll
            for (int ks = 0; ks < 2; ++ks) {
                bf16x8 kb = *(const bf16x8*)(KsB + r*128 + (((g + 4*ks) ^ sz) * 16));
                s[nt] = __builtin_amdgcn_mfma_f32_16x16x32_bf16(kb, qa[ks], s[nt], 0, 0, 0);
            }
        }
        if (kv == qt) {              // diagonal: mask kv_local > q_local
#pragma unroll
            for (int nt = 0; nt < 4; ++nt) {
                const int kb0 = 32*(nt >> 1) + 4*(nt & 1) + 8*g;
#pragma unroll
                for (int reg = 0; reg < 4; ++reg)
                    if (kb0 + reg > w*16 + li) s[nt][reg] = -INFINITY;
            }
        }

        // ---- softmax (raw-domain max, scaled via fma into exp2)
        float mx = s[0][0];
#pragma unroll
        for (int nt = 0; nt < 4; ++nt)
#pragma unroll
            for (int reg = 0; reg < 4; ++reg) mx = fmaxf(mx, s[nt][reg]);
        mx = fmaxf(mx, __shfl_xor(mx, 16));
        mx = fmaxf(mx, __shfl_xor(mx, 32));
        mx *= SCL2E;
        if (mx > m_i + 8.f) {        // defer-max: rescale only on real growth
            const float sc = exp2f(m_i - mx);
            m_i = mx;
            l_i *= sc;
#pragma unroll
            for (int n2 = 0; n2 < 4; ++n2) ctx[n2] *= sc;
        }
        float rs = 0.f;
#pragma unroll
        for (int nt = 0; nt < 4; ++nt)
#pragma unroll
            for (int reg = 0; reg < 4; ++reg) {
                const float p = exp2f(fmaf(s[nt][reg], SCL2E, -m_i));
                s[nt][reg] = p;
                rs += p;
            }
        rs += __shfl_xor(rs, 16);
        rs += __shfl_xor(rs, 32);
        l_i += rs;

        // ---- pack P in-register: pk[nt][wd] covers kv pair; B-frags assemble free
        unsigned pk[4][2];
#pragma unroll
        for (int nt = 0; nt < 4; ++nt) {
            pk[nt][0] = cvt_pk_bf16(s[nt][0], s[nt][1]);
            pk[nt][1] = cvt_pk_bf16(s[nt][2], s[nt][3]);
        }

        // ---- PV: ctx^T += V^T P^T
#pragma unroll
        for (int ks2 = 0; ks2 < 2; ++ks2) {
            union { unsigned u[4]; bf16x8 v; } pf;
            pf.u[0] = pk[2*ks2][0]; pf.u[1] = pk[2*ks2][1];
            pf.u[2] = pk[2*ks2+1][0]; pf.u[3] = pk[2*ks2+1][1];
#pragma unroll
            for (int n2 = 0; n2 < 4; ++n2) {
                const int r  = n2*16 + li;
                const int sz = (li & 3) | ((li & 8) >> 1);
                bf16x8 vb = *(const bf16x8*)(VTB + r*128 + (((g + 4*ks2) ^ sz) * 16));
                ctx[n2] = __builtin_amdgcn_mfma_f32_16x16x32_bf16(vb, pf.v, ctx[n2], 0, 0, 0);
            }
        }
    }

    // ---- normalize + write (pairs packed to u32: d = n2*16 + 4g + {0..3})
    const float inv = 1.f / l_i;
    const size_t row = rowbase + q0 + w*16 + li;
    unsigned* Ou = (unsigned*)O;
#pragma unroll
    for (int n2 = 0; n2 < 4; ++n2) {
        const size_t base = (row * DIM + h*HD + n2*16 + 4*g) >> 1;
        Ou[base    ] = cvt_pk_bf16(ctx[n2][0]*inv, ctx[n2][1]*inv);
        Ou[base + 1] = cvt_pk_bf16(ctx[n2][2]*inv, ctx[n2][3]*inv);
    }
}

// ---------------------------------------------------------------------------
extern "C" void kernel_launch(void* const* d_in, const int* in_sizes, int n_in,
                              void* d_out, int out_size, void* d_ws, size_t ws_size,
                              hipStream_t stream)
{
    const float* x  = (const float*)d_in[0];
    const float* Wq = (const float*)d_in[1];
    const float* Wk = (const float*)d_in[2];
    const float* Wv = (const float*)d_in[3];
    const float* Wo = (const float*)d_in[4];
    const float* bo = (const float*)d_in[5];
    float* out = (float*)d_out;

    char* ws = (char*)d_ws;
    unsigned short* xb    = (unsigned short*)(ws);                 // 16 MB
    unsigned short* qkv   = (unsigned short*)(ws + (16u << 20));   // 48 MB [8192][3072]
    unsigned short* ctb   = (unsigned short*)(ws + (64u << 20));   // 16 MB
    unsigned short* WTall = (unsigned short*)(ws + (80u << 20));   // 6 MB  [3072][1024]
    unsigned short* WoT   = (unsigned short*)(ws + (86u << 20));   // 2 MB

    cvt_x<<<MTOT*DIM/8/256, 256, 0, stream>>>(x, xb, MTOT*DIM/8);
    dim3 tb(32, 8), tg(32, 32);
    cvt_tr<<<tg, tb, 0, stream>>>(Wq, WTall);
    cvt_tr<<<tg, tb, 0, stream>>>(Wk, WTall + (size_t)DIM*DIM);
    cvt_tr<<<tg, tb, 0, stream>>>(Wv, WTall + (size_t)2*DIM*DIM);
    cvt_tr<<<tg, tb, 0, stream>>>(Wo, WoT);

    gemm_glds<false><<<dim3(MTOT/128, LDQKV/128), 256, 0, stream>>>(
        xb, WTall, nullptr, qkv, MTOT, LDQKV, DIM);

    attn_bf16<<<dim3(TSEQ/64, BATCH*NH), 256, 0, stream>>>(qkv, ctb);

    gemm_glds<true><<<dim3(MTOT/128, DIM/128), 256, 0, stream>>>(
        ctb, WoT, bo, out, MTOT, DIM, DIM);
}